// Round 3
// baseline (194.774 us; speedup 1.0000x reference)
//
#include <hip/hip_runtime.h>

// RPN anchor-target assignment. B=8, A=184320, G=64.
// Outputs (flat float32, concatenated): labels[B*A], matched[B*A*4], max_iou[B*A].
// Requires A % 512 == 0 (184320 = 360*512).
//
// Sparse-mask strategy, 3 kernels (no device fences — R6 showed per-block
// __threadfence() is an L2-flush-scale stall on CDNA4). Per batch, 4 quantized
// interval tables (u64[128], 5px strips) over the 64 gts are built once; each
// anchor gets a conservative superset mask of possibly-overlapping gts (4 LDS
// lookups + 3 ands), then runs the exact IEEE IoU loop only over mask bits
// (~10 avg). Skipped pairs have true iou==0, handled exactly by maxv init 0 /
// KEY_INIT. Column argmax via LDS u64 atomicMax; block->global device atomicMax.
//
// R10 (this round): attack the measured LDS-pipe co-limit (2.32M conflict
// cycles ~ 8% of kernel cycles; 5 random-bank gt reads per pair).
//  - gt coords live in lane registers (lane l of every wave holds gt[l]'s
//    x0,y0,x1,y1,area); per-pair fetch is 5 conflict-free ds_bpermute pulls
//    from lane g instead of 5 ~4-way-conflicted LDS reads. SoA LDS deleted.
//  - Pair loop made uniform-EXEC (bpermute from inactive lanes is undefined):
//    all 64 lanes iterate wave-max times; exhausted lanes eval a dummy pair
//    (g = ctz(m | top-bit) = 63). Exact by construction: every eval computes a
//    TRUE iou (out-of-mask => inter=0 => iou=0 => key <= KEY_INIT no-op;
//    repeats idempotent under max; ascending order + strict > keeps numpy
//    first-max). No masking fixups needed.
//  - Two u32 half-loops merged into one u64-mask loop (wave-max of full mask,
//    ~-20% iterations for +4 ops/iter).
//  - fg epilogue matched-box gather now a (rare, divergent-safe) global read.

constexpr int B = 8;
constexpr int G = 64;
constexpr int BLOCK = 256;
constexpr int APT = 2;                 // anchors per thread
constexpr int ABLK = BLOCK * APT;      // anchors per block = 512
constexpr int NSTRIP = 128;            // 5px strips
constexpr float STRIP_SCALE = 0.2f;
constexpr float STRIP_W = 5.0f;
constexpr float IMG = 640.0f;
constexpr float FG_IOU = 0.7f;
constexpr float BG_IOU = 0.3f;
constexpr float SLACK = 1.0f;
// key(iou=0, anchor=0): correct for an all-zero column (numpy argmax = 0).
constexpr unsigned long long KEY_INIT = 0xFFFFFFFFull;

// ws layout: [256]   u64 gkeys[B*G]      (0xAA poison < 0 as i64 == -inf)
//            [8192]  u64 tabs[B][4][128] (built by build_tables each launch)

// tab0 (xlo): gt.x0 < (s+1)*5 + SLACK   used at s=strip(ax1)  ⊇ gt.x0 < ax1
// tab1 (xhi): gt.x1 > s*5 - SLACK       used at s=strip(ax0)  ⊇ gt.x1 > ax0
// tab2 (ylo): gt.y0 < (s+1)*5 + SLACK   used at s=strip(ay1)  ⊇ gt.y0 < ay1
// tab3 (yhi): gt.y1 > s*5 - SLACK       used at s=strip(ay0)  ⊇ gt.y1 > ay0
__global__ __launch_bounds__(512) void build_tables(
    const float4* __restrict__ gt, unsigned long long* __restrict__ tabs) {
    __shared__ float4 sgt[G];
    const int b = blockIdx.x;
    const int t = threadIdx.x;          // 0..511 = tabIdx*128 + strip
    if (t < G) sgt[t] = gt[b * G + t];
    __syncthreads();
    const int tabIdx = t >> 7;
    const int strip = t & 127;
    const int comp = (tabIdx == 0) ? 0 : (tabIdx == 1) ? 2 : (tabIdx == 2) ? 1 : 3;
    const bool hi = (tabIdx & 1) != 0;
    const float thr = hi ? (strip * STRIP_W - SLACK)
                         : ((strip + 1) * STRIP_W + SLACK);
    unsigned long long m = 0ull;
    for (int g = 0; g < G; ++g) {
        float c = ((const float*)&sgt[g])[comp];
        bool in = hi ? (c > thr) : (c < thr);
        if (in) m |= (1ull << g);
    }
    tabs[(size_t)b * 512 + t] = m;
}

__device__ __forceinline__ float bpf(int a4, float v) {
    return __int_as_float(__builtin_amdgcn_ds_bpermute(a4, __float_as_int(v)));
}

__global__ __launch_bounds__(BLOCK) void assign_main(
    const float4* __restrict__ anchors,   // [B*A] cxcywh
    const float4* __restrict__ gt,        // [B*G] xyxy
    float* __restrict__ L,                // labels out [B*A]
    float4* __restrict__ M,               // matched out [B*A]
    float* __restrict__ V,                // max_iou out [B*A]
    long long* __restrict__ gkeys,        // [B*G] global argmax keys (signed max)
    const unsigned long long* __restrict__ tabs,
    int A, int bpb) {
#pragma clang fp contract(off)
    __shared__ unsigned long long tab[4][NSTRIP];
    __shared__ unsigned long long skey[G];

    const int b = blockIdx.x / bpb;
    const int t = threadIdx.x;
    const int base = (blockIdx.x % bpb) * ABLK;

    if (t < G) skey[t] = KEY_INIT;
    {   // 4 KB table: one ulonglong2 (16B) per thread
        const ulonglong2* src = (const ulonglong2*)(tabs + (size_t)b * 512);
        ((ulonglong2*)&tab[0][0])[t] = src[t];
    }

    // gt register file: lane l of each wave holds gt[l] (x0,y0,x1,y1,area).
    // Per-pair fetch = 5 conflict-free ds_bpermute pulls from lane g.
    const int lane = t & 63;
    const float4 gl = gt[(size_t)b * G + lane];
    const float rgx0 = gl.x, rgy0 = gl.y, rgx1 = gl.z, rgy1 = gl.w;
    const float rga = (gl.z - gl.x) * (gl.w - gl.y);   // numpy area order

    __syncthreads();

    // Both anchors' loads issued up front: iteration 1's global latency hides
    // under iteration 0's compute.
    const int a0 = base + t;
    const int a1 = base + BLOCK + t;
    const size_t idx0 = (size_t)b * A + a0;
    const size_t idx1 = (size_t)b * A + a1;
    const float4 anbuf[APT] = { anchors[idx0], anchors[idx1] };

#pragma unroll
    for (int j = 0; j < APT; ++j) {
        const int a = j == 0 ? a0 : a1;
        const size_t idx = j == 0 ? idx0 : idx1;
        const float4 an = anbuf[j];
        float ax0 = an.x - 0.5f * an.z;
        float ay0 = an.y - 0.5f * an.w;
        float ax1 = an.x + 0.5f * an.z;
        float ay1 = an.y + 0.5f * an.w;
        float area_a = (ax1 - ax0) * (ay1 - ay0);   // must match numpy (corner-derived)

        int sx0 = (int)(ax0 * STRIP_SCALE); sx0 = sx0 < 0 ? 0 : (sx0 > 127 ? 127 : sx0);
        int sx1 = (int)(ax1 * STRIP_SCALE); sx1 = sx1 < 0 ? 0 : (sx1 > 127 ? 127 : sx1);
        int sy0 = (int)(ay0 * STRIP_SCALE); sy0 = sy0 < 0 ? 0 : (sy0 > 127 ? 127 : sy0);
        int sy1 = (int)(ay1 * STRIP_SCALE); sy1 = sy1 < 0 ? 0 : (sy1 > 127 ? 127 : sy1);

        unsigned long long m =
            tab[0][sx1] & tab[1][sx0] & tab[2][sy1] & tab[3][sy0];

        float maxv = 0.0f;   // all-masked row => max_iou 0, argmax 0 (numpy exact)
        int maxg = 0;
        const unsigned long long inv_p =
            (unsigned long long)(0xFFFFFFFFu - (unsigned)a);

        // Uniform-EXEC u64-mask loop: all 64 lanes iterate wave-max times.
        // Exhausted lanes eval dummy pair g=63 (true iou, idempotent, no-op
        // key). Ascending g + strict > preserves numpy first-max. Prefetch of
        // next pair's coords (bpermute) issued before the current math+div.
        if (__any(m != 0ull)) {
            int g = (int)__builtin_ctzll(m | 0x8000000000000000ull);
            m &= m - 1;
            int a4 = g << 2;
            float gx0 = bpf(a4, rgx0), gy0 = bpf(a4, rgy0);
            float gx1 = bpf(a4, rgx1), gy1 = bpf(a4, rgy1);
            float sa  = bpf(a4, rga);
            for (;;) {
                const bool anymore = __any(m != 0ull);   // wave-uniform
                const int gn = (int)__builtin_ctzll(m | 0x8000000000000000ull);
                m &= m - 1;                              // 0 stays 0
                const int n4 = gn << 2;
                const float nx0 = bpf(n4, rgx0), ny0 = bpf(n4, rgy0);
                const float nx1 = bpf(n4, rgx1), ny1 = bpf(n4, rgy1);
                const float nsa = bpf(n4, rga);

                float lx = fmaxf(ax0, gx0);
                float ly = fmaxf(ay0, gy0);
                float rx = fminf(ax1, gx1);
                float ry = fminf(ay1, gy1);
                float w = fmaxf(rx - lx, 0.0f);
                float h = fmaxf(ry - ly, 0.0f);
                float inter = w * h;
                float uni = area_a + sa - inter;
                float iou = inter / uni;         // IEEE div: bit-exact vs numpy

                bool better = iou > maxv;
                maxv = better ? iou : maxv;
                maxg = better ? g : maxg;

                // iou==0 => key = inv_p <= KEY_INIT: atomicMax is a natural
                // no-op (skey[g] >= KEY_INIT always). No zero-select needed.
                unsigned long long key =
                    ((unsigned long long)__float_as_uint(iou) << 32) | inv_p;
                atomicMax(&skey[g], key);

                if (!anymore) break;
                g = gn;
                gx0 = nx0; gy0 = ny0; gx1 = nx1; gy1 = ny1; sa = nsa;
            }
        }

        bool fg = maxv > FG_IOU;
        bool bg = maxv < BG_IOU;
        bool cross = (ax0 < 0.0f) || (ay0 < 0.0f) || (ax1 > IMG) || (ay1 > IMG);

        L[idx] = cross ? -1.0f : (fg ? 1.0f : (bg ? 0.0f : -1.0f));
        float4 mbox = make_float4(0.0f, 0.0f, 0.0f, 0.0f);
        if (fg) mbox = gt[(size_t)b * G + maxg];  // rare; divergent-safe global
        M[idx] = mbox;
        V[idx] = maxv;
    }

    __syncthreads();
    if (t < G) {
        // unconditional: every column must receive >= KEY_INIT (gkeys poisoned)
        atomicMax(&gkeys[b * G + t], (long long)skey[t]);
    }
}

// Rule 1 fixup: one block per batch, thread per gt. numpy scatter is
// last-write-wins; thread g writes only if no later g' targets the same anchor.
__global__ void fixup(
    const float4* __restrict__ anchors,
    const float4* __restrict__ gt,
    const long long* __restrict__ gkeys,
    float* __restrict__ L,
    float4* __restrict__ M,
    const float* __restrict__ V,
    int A) {
#pragma clang fp contract(off)
    const int b = blockIdx.x;
    const int g = threadIdx.x;
    __shared__ int tgt[G];

    unsigned long long key = (unsigned long long)gkeys[b * G + g];
    unsigned int a = 0xFFFFFFFFu - (unsigned int)(key & 0xFFFFFFFFull);
    tgt[g] = (int)a;
    __syncthreads();

    bool write = true;
    for (int g2 = g + 1; g2 < G; ++g2)
        if (tgt[g2] == (int)a) { write = false; break; }
    if (!write) return;

    const size_t idx = (size_t)b * A + a;
    float4 an = anchors[idx];
    float ax0 = an.x - 0.5f * an.z;
    float ay0 = an.y - 0.5f * an.w;
    float ax1 = an.x + 0.5f * an.z;
    float ay1 = an.y + 0.5f * an.w;
    bool cross = (ax0 < 0.0f) || (ay0 < 0.0f) || (ax1 > IMG) || (ay1 > IMG);
    // Rule 1 label=1 overrides rule-3 bg; cross filter still wins.
    L[idx] = cross ? -1.0f : 1.0f;
    // Rule 2 (fg) overrides rule 1's matched box; otherwise rule 1 assigns gt[g].
    if (!(V[idx] > FG_IOU)) M[idx] = gt[b * G + g];
}

extern "C" void kernel_launch(void* const* d_in, const int* in_sizes, int n_in,
                              void* d_out, int out_size, void* d_ws, size_t ws_size,
                              hipStream_t stream) {
    const float4* anchors = (const float4*)d_in[0];
    const float4* gt      = (const float4*)d_in[1];
    const int A = in_sizes[0] / (B * 4);

    float* out = (float*)d_out;
    float*  L = out;                                 // [B*A]
    float4* M = (float4*)(out + (size_t)B * A);      // [B*A] float4
    float*  V = out + (size_t)B * A * 5;             // [B*A]

    char* ws = (char*)d_ws;
    long long* gkeys = (long long*)(ws + 256);       // poison 0xAA.. == -inf (i64)
    unsigned long long* tabs = (unsigned long long*)(ws + 8192);  // B*4*128 u64

    const int bpb = A / ABLK;                        // 184320/512 = 360
    build_tables<<<B, 512, 0, stream>>>(gt, tabs);
    assign_main<<<B * bpb, BLOCK, 0, stream>>>(anchors, gt, L, M, V, gkeys,
                                               tabs, A, bpb);
    fixup<<<B, G, 0, stream>>>(anchors, gt, gkeys, L, M, V, A);
}

// Round 4
// 120.979 us; speedup vs baseline: 1.6100x; 1.6100x over previous
//
#include <hip/hip_runtime.h>

// RPN anchor-target assignment. B=8, A=184320, G=64.
// Outputs (flat float32, concatenated): labels[B*A], matched[B*A*4], max_iou[B*A].
// Requires A % 768 == 0 (184320 = 240*768).
//
// Sparse-mask strategy, 3 kernels (no device fences — R6 showed per-block
// __threadfence() is an L2-flush-scale stall on CDNA4). Per batch, 4 quantized
// interval tables (u64[128], 5px strips) over the 64 gts are built once; each
// anchor gets a conservative superset mask of possibly-overlapping gts (4 LDS
// lookups + 3 ands), then runs the exact IEEE IoU loop only over mask bits
// (~10 avg). Skipped pairs have true iou==0, handled exactly by maxv init 0 /
// KEY_INIT. gt coords SoA in LDS (scalar b32 reads; b128 gather was 8-way
// conflicted per R7 PMC). Column argmax via LDS u64 atomicMax; block->global
// via device atomicMax.
//
// R11 (this round): R10's bpermute/uniform-EXEC experiment REVERTED (10x bank
// conflicts, 123us — ds_bpermute is expensive on gfx950 and uniform-EXEC
// forced dummy work on exhausted lanes). Back to R9 structure, plus:
//  - Diagnosis: R9 was dependency-latency-bound (per-SIMD issue ~22%; ~100cy
//    dependent chain per pair vs ~60cy issued, only ~3.7 waves/SIMD resident).
//  - 2-way ILP: each lane processes TWO of its own mask bits per iteration;
//    the two independent IoU chains interleave in the issue slots. Sequential
//    max-updates keep numpy first-max order; odd tail duplicates the last bit
//    (idempotent: second compare fails, same-key atomicMax is a no-op).
//  - APT 2->3 (BLOCK=256 kept): grid 2880->1920 = 7.5 blocks/CU, whole grid
//    resident in one dispatch round (removes the ragged second-round tail that
//    capped time-averaged occupancy at 47%).

constexpr int B = 8;
constexpr int G = 64;
constexpr int BLOCK = 256;
constexpr int APT = 3;                 // anchors per thread
constexpr int ABLK = BLOCK * APT;      // anchors per block = 768
constexpr int NSTRIP = 128;            // 5px strips
constexpr float STRIP_SCALE = 0.2f;
constexpr float STRIP_W = 5.0f;
constexpr float IMG = 640.0f;
constexpr float FG_IOU = 0.7f;
constexpr float BG_IOU = 0.3f;
constexpr float SLACK = 1.0f;
// key(iou=0, anchor=0): correct for an all-zero column (numpy argmax = 0).
constexpr unsigned long long KEY_INIT = 0xFFFFFFFFull;

// ws layout: [256]   u64 gkeys[B*G]      (0xAA poison < 0 as i64 == -inf)
//            [8192]  u64 tabs[B][4][128] (built by build_tables each launch)

// tab0 (xlo): gt.x0 < (s+1)*5 + SLACK   used at s=strip(ax1)  ⊇ gt.x0 < ax1
// tab1 (xhi): gt.x1 > s*5 - SLACK       used at s=strip(ax0)  ⊇ gt.x1 > ax0
// tab2 (ylo): gt.y0 < (s+1)*5 + SLACK   used at s=strip(ay1)  ⊇ gt.y0 < ay1
// tab3 (yhi): gt.y1 > s*5 - SLACK       used at s=strip(ay0)  ⊇ gt.y1 > ay0
__global__ __launch_bounds__(512) void build_tables(
    const float4* __restrict__ gt, unsigned long long* __restrict__ tabs) {
    __shared__ float4 sgt[G];
    const int b = blockIdx.x;
    const int t = threadIdx.x;          // 0..511 = tabIdx*128 + strip
    if (t < G) sgt[t] = gt[b * G + t];
    __syncthreads();
    const int tabIdx = t >> 7;
    const int strip = t & 127;
    const int comp = (tabIdx == 0) ? 0 : (tabIdx == 1) ? 2 : (tabIdx == 2) ? 1 : 3;
    const bool hi = (tabIdx & 1) != 0;
    const float thr = hi ? (strip * STRIP_W - SLACK)
                         : ((strip + 1) * STRIP_W + SLACK);
    unsigned long long m = 0ull;
    for (int g = 0; g < G; ++g) {
        float c = ((const float*)&sgt[g])[comp];
        bool in = hi ? (c > thr) : (c < thr);
        if (in) m |= (1ull << g);
    }
    tabs[(size_t)b * 512 + t] = m;
}

__global__ __launch_bounds__(BLOCK) void assign_main(
    const float4* __restrict__ anchors,   // [B*A] cxcywh
    const float4* __restrict__ gt,        // [B*G] xyxy
    float* __restrict__ L,                // labels out [B*A]
    float4* __restrict__ M,               // matched out [B*A]
    float* __restrict__ V,                // max_iou out [B*A]
    long long* __restrict__ gkeys,        // [B*G] global argmax keys (signed max)
    const unsigned long long* __restrict__ tabs,
    int A, int bpb) {
#pragma clang fp contract(off)
    __shared__ float sgx0[G], sgy0[G], sgx1[G], sgy1[G], sga[G];  // SoA: b32 reads
    __shared__ unsigned long long tab[4][NSTRIP];
    __shared__ unsigned long long skey[G];

    const int b = blockIdx.x / bpb;
    const int t = threadIdx.x;
    const int base = (blockIdx.x % bpb) * ABLK;

    if (t < G) {
        float4 gb = gt[b * G + t];
        sgx0[t] = gb.x; sgy0[t] = gb.y; sgx1[t] = gb.z; sgy1[t] = gb.w;
        sga[t] = (gb.z - gb.x) * (gb.w - gb.y);
        skey[t] = KEY_INIT;
    }
    {   // 4 KB table: one ulonglong2 (16B) per thread
        const ulonglong2* src = (const ulonglong2*)(tabs + (size_t)b * 512);
        ((ulonglong2*)&tab[0][0])[t] = src[t];
    }
    __syncthreads();

    // All anchors' loads issued up front: later iterations' global latency
    // hides under earlier compute.
    float4 anbuf[APT];
    size_t idxs[APT];
    int as[APT];
#pragma unroll
    for (int j = 0; j < APT; ++j) {
        as[j] = base + j * BLOCK + t;
        idxs[j] = (size_t)b * A + as[j];
        anbuf[j] = anchors[idxs[j]];
    }

#pragma unroll
    for (int j = 0; j < APT; ++j) {
        const int a = as[j];
        const size_t idx = idxs[j];
        const float4 an = anbuf[j];
        float ax0 = an.x - 0.5f * an.z;
        float ay0 = an.y - 0.5f * an.w;
        float ax1 = an.x + 0.5f * an.z;
        float ay1 = an.y + 0.5f * an.w;
        float area_a = (ax1 - ax0) * (ay1 - ay0);   // must match numpy (corner-derived)

        int sx0 = (int)(ax0 * STRIP_SCALE); sx0 = sx0 < 0 ? 0 : (sx0 > 127 ? 127 : sx0);
        int sx1 = (int)(ax1 * STRIP_SCALE); sx1 = sx1 < 0 ? 0 : (sx1 > 127 ? 127 : sx1);
        int sy0 = (int)(ay0 * STRIP_SCALE); sy0 = sy0 < 0 ? 0 : (sy0 > 127 ? 127 : sy0);
        int sy1 = (int)(ay1 * STRIP_SCALE); sy1 = sy1 < 0 ? 0 : (sy1 > 127 ? 127 : sy1);

        unsigned long long mask =
            tab[0][sx1] & tab[1][sx0] & tab[2][sy1] & tab[3][sy0];

        float maxv = 0.0f;   // all-masked row => max_iou 0, argmax 0 (numpy exact)
        int maxg = 0;
        const unsigned long long inv_p =
            (unsigned long long)(0xFFFFFFFFu - (unsigned)a);

        // Two u32 half-loops, divergent-exec (exhausted lanes masked off).
        // 2-way ILP: two of the lane's own bits per iteration; the two
        // independent IoU chains interleave in the issue slots. Sequential
        // max-updates keep numpy first-max. Odd tail duplicates the last bit
        // (idempotent: equal iou fails strict >, same-key atomicMax no-ops).
        auto half = [&](unsigned m, int gbase) {
            while (m) {
                const int g1 = gbase + (int)__builtin_ctz(m);
                m &= m - 1;
                const int cand = gbase + (int)__builtin_ctz(m | 0x80000000u);
                const int g2 = m ? cand : g1;      // duplicate g1 on odd tail
                m &= m - 1;                        // 0 stays 0

                const float gx0a = sgx0[g1], gy0a = sgy0[g1];
                const float gx1a = sgx1[g1], gy1a = sgy1[g1];
                const float saa  = sga[g1];
                const float gx0b = sgx0[g2], gy0b = sgy0[g2];
                const float gx1b = sgx1[g2], gy1b = sgy1[g2];
                const float sab  = sga[g2];

                float lxa = fmaxf(ax0, gx0a), lya = fmaxf(ay0, gy0a);
                float rxa = fminf(ax1, gx1a), rya = fminf(ay1, gy1a);
                float wa = fmaxf(rxa - lxa, 0.0f), ha = fmaxf(rya - lya, 0.0f);
                float intera = wa * ha;
                float unia = area_a + saa - intera;
                float ioua = intera / unia;        // IEEE div: bit-exact vs numpy

                float lxb = fmaxf(ax0, gx0b), lyb = fmaxf(ay0, gy0b);
                float rxb = fminf(ax1, gx1b), ryb = fminf(ay1, gy1b);
                float wb = fmaxf(rxb - lxb, 0.0f), hb = fmaxf(ryb - lyb, 0.0f);
                float interb = wb * hb;
                float unib = area_a + sab - interb;
                float ioub = interb / unib;        // IEEE div: bit-exact vs numpy

                bool b1 = ioua > maxv;
                maxv = b1 ? ioua : maxv;
                maxg = b1 ? g1 : maxg;
                bool b2 = ioub > maxv;
                maxv = b2 ? ioub : maxv;
                maxg = b2 ? g2 : maxg;

                // iou==0 => key = inv_p <= KEY_INIT: atomicMax is a natural
                // no-op (skey[g] >= KEY_INIT always). No zero-select needed.
                unsigned long long key1 =
                    ((unsigned long long)__float_as_uint(ioua) << 32) | inv_p;
                unsigned long long key2 =
                    ((unsigned long long)__float_as_uint(ioub) << 32) | inv_p;
                atomicMax(&skey[g1], key1);
                atomicMax(&skey[g2], key2);
            }
        };
        half((unsigned)mask, 0);
        half((unsigned)(mask >> 32), 32);

        bool fg = maxv > FG_IOU;
        bool bg = maxv < BG_IOU;
        bool cross = (ax0 < 0.0f) || (ay0 < 0.0f) || (ax1 > IMG) || (ay1 > IMG);

        L[idx] = cross ? -1.0f : (fg ? 1.0f : (bg ? 0.0f : -1.0f));
        float4 mbox = make_float4(0.0f, 0.0f, 0.0f, 0.0f);
        if (fg)  // rare: usually whole-wave skipped; SoA gather (4 b32 reads)
            mbox = make_float4(sgx0[maxg], sgy0[maxg], sgx1[maxg], sgy1[maxg]);
        M[idx] = mbox;
        V[idx] = maxv;
    }

    __syncthreads();
    if (t < G) {
        // unconditional: every column must receive >= KEY_INIT (gkeys poisoned)
        atomicMax(&gkeys[b * G + t], (long long)skey[t]);
    }
}

// Rule 1 fixup: one block per batch, thread per gt. numpy scatter is
// last-write-wins; thread g writes only if no later g' targets the same anchor.
__global__ void fixup(
    const float4* __restrict__ anchors,
    const float4* __restrict__ gt,
    const long long* __restrict__ gkeys,
    float* __restrict__ L,
    float4* __restrict__ M,
    const float* __restrict__ V,
    int A) {
#pragma clang fp contract(off)
    const int b = blockIdx.x;
    const int g = threadIdx.x;
    __shared__ int tgt[G];

    unsigned long long key = (unsigned long long)gkeys[b * G + g];
    unsigned int a = 0xFFFFFFFFu - (unsigned int)(key & 0xFFFFFFFFull);
    tgt[g] = (int)a;
    __syncthreads();

    bool write = true;
    for (int g2 = g + 1; g2 < G; ++g2)
        if (tgt[g2] == (int)a) { write = false; break; }
    if (!write) return;

    const size_t idx = (size_t)b * A + a;
    float4 an = anchors[idx];
    float ax0 = an.x - 0.5f * an.z;
    float ay0 = an.y - 0.5f * an.w;
    float ax1 = an.x + 0.5f * an.z;
    float ay1 = an.y + 0.5f * an.w;
    bool cross = (ax0 < 0.0f) || (ay0 < 0.0f) || (ax1 > IMG) || (ay1 > IMG);
    // Rule 1 label=1 overrides rule-3 bg; cross filter still wins.
    L[idx] = cross ? -1.0f : 1.0f;
    // Rule 2 (fg) overrides rule 1's matched box; otherwise rule 1 assigns gt[g].
    if (!(V[idx] > FG_IOU)) M[idx] = gt[b * G + g];
}

extern "C" void kernel_launch(void* const* d_in, const int* in_sizes, int n_in,
                              void* d_out, int out_size, void* d_ws, size_t ws_size,
                              hipStream_t stream) {
    const float4* anchors = (const float4*)d_in[0];
    const float4* gt      = (const float4*)d_in[1];
    const int A = in_sizes[0] / (B * 4);

    float* out = (float*)d_out;
    float*  L = out;                                 // [B*A]
    float4* M = (float4*)(out + (size_t)B * A);      // [B*A] float4
    float*  V = out + (size_t)B * A * 5;             // [B*A]

    char* ws = (char*)d_ws;
    long long* gkeys = (long long*)(ws + 256);       // poison 0xAA.. == -inf (i64)
    unsigned long long* tabs = (unsigned long long*)(ws + 8192);  // B*4*128 u64

    const int bpb = A / ABLK;                        // 184320/768 = 240
    build_tables<<<B, 512, 0, stream>>>(gt, tabs);
    assign_main<<<B * bpb, BLOCK, 0, stream>>>(anchors, gt, L, M, V, gkeys,
                                               tabs, A, bpb);
    fixup<<<B, G, 0, stream>>>(anchors, gt, gkeys, L, M, V, A);
}